// Round 9
// baseline (260.133 us; speedup 1.0000x reference)
//
#include <hip/hip_runtime.h>
#include <stdint.h>

#define B_   4
#define S_   2048
#define DI   1024
#define DOUT 1024
#define NHD  16
#define HD   64

typedef __attribute__((ext_vector_type(8))) short short8;
typedef __attribute__((ext_vector_type(4))) float f32x4;
typedef __attribute__((ext_vector_type(16))) float f32x16;

__device__ __forceinline__ unsigned short f32_bf16(float f) {
  union { float f; unsigned u; } v; v.f = f;
  unsigned r = v.u + 0x7FFFu + ((v.u >> 16) & 1u);   // RNE
  return (unsigned short)(r >> 16);
}

// packed f32x2 -> bf16x2 (dst.lo = bf16(a), dst.hi = bf16(b))
__device__ __forceinline__ unsigned cvt_pk_bf16(float a, float b) {
  unsigned r;
  asm("v_cvt_pk_bf16_f32 %0, %1, %2" : "=v"(r) : "v"(a), "v"(b));
  return r;
}

// v_permlane32_swap_b32 a, b:  a.row1 <-> b.row0  (rows = 32-lane halves)
__device__ __forceinline__ void pl32swap(unsigned &dst, unsigned &src) {
  asm("v_permlane32_swap_b32 %0, %1" : "+v"(dst), "+v"(src));
}

__device__ __forceinline__ float max3f(float a, float b, float c) {
  float d;
  asm("v_max3_f32 %0, %1, %2, %3" : "=v"(d) : "v"(a), "v"(b), "v"(c));
  return d;
}

// async 16B global->LDS (dst wave-uniform; HW adds lane*16)
__device__ __forceinline__ void gl_lds16(const void* g, void* s) {
  __builtin_amdgcn_global_load_lds(
      (const __attribute__((address_space(1))) unsigned int*)g,
      (__attribute__((address_space(3))) unsigned int*)s, 16, 0, 0);
}

#define EXP2(x) __builtin_amdgcn_exp2f(x)

// ---------- elementwise fp32 -> bf16 ----------
__global__ __launch_bounds__(256) void cvt_kernel(const float* __restrict__ src,
                                                  unsigned short* __restrict__ dst, int n4) {
  int i = blockIdx.x * blockDim.x + threadIdx.x;
  if (i < n4) {
    float4 v = ((const float4*)src)[i];
    ushort4 o;
    o.x = f32_bf16(v.x); o.y = f32_bf16(v.y); o.z = f32_bf16(v.z); o.w = f32_bf16(v.w);
    ((ushort4*)dst)[i] = o;
  }
}

// ---------- weight transpose+convert x4: W[k][n] f32 -> Wt[n][k] bf16 ----------
__global__ __launch_bounds__(256) void wtrans4_kernel(
    const float* __restrict__ W0, const float* __restrict__ W1,
    const float* __restrict__ W2, const float* __restrict__ W3,
    unsigned short* __restrict__ T0, unsigned short* __restrict__ T1,
    unsigned short* __restrict__ T2, unsigned short* __restrict__ T3) {
  __shared__ __attribute__((aligned(16))) float tile[64][65];
  const int z = blockIdx.z;
  const float* W = z == 0 ? W0 : z == 1 ? W1 : z == 2 ? W2 : W3;
  unsigned short* Wt = z == 0 ? T0 : z == 1 ? T1 : z == 2 ? T2 : T3;
  const int k0 = blockIdx.y * 64;
  const int n0 = blockIdx.x * 64;
  const int tid = threadIdx.x;
#pragma unroll
  for (int i = 0; i < 4; i++) {
    int c = tid + i * 256;
    int r = c >> 4;
    int cc = (c & 15) * 4;
    float4 v = *(const float4*)(W + (size_t)(k0 + r) * DOUT + n0 + cc);
    tile[r][cc] = v.x; tile[r][cc + 1] = v.y; tile[r][cc + 2] = v.z; tile[r][cc + 3] = v.w;
  }
  __syncthreads();
#pragma unroll
  for (int i = 0; i < 4; i++) {
    int c = tid + i * 256;
    int r = c >> 4;
    int cc = (c & 15) * 4;
    ushort4 o;
    o.x = f32_bf16(tile[cc + 0][r]);
    o.y = f32_bf16(tile[cc + 1][r]);
    o.z = f32_bf16(tile[cc + 2][r]);
    o.w = f32_bf16(tile[cc + 3][r]);
    *(ushort4*)(Wt + (size_t)(n0 + r) * DI + k0 + cc) = o;
  }
}

// swizzled index into the 128x128 bf16 C-stage tile (16B-chunk XOR swizzle).
__device__ __forceinline__ int cswz(int r, int c) {
  return r * 128 + ((((c >> 3) ^ ((r >> 3) & 15)) << 3) | (c & 7));
}

// ---------- GEMM (round-5 proven: m97 recipe + stage-early double-buffer) ----
// + bijective XCD-chunk swizzle: XCD k owns x-strip [8k,8k+8) for all y ->
// its 8 A-panels (2 MB) stay L2-resident across the whole y-sweep.
// MODE 0: fused QKV (N=3072); Q/K scatter head-major, V written transposed
// to Vt[bh][hd][s] via LDS cswz tile. MODE 1: fp32 row-major + bias.
template <int MODE>
__global__ __launch_bounds__(256) void gemm_kernel(
    const unsigned short* __restrict__ A,
    const unsigned short* __restrict__ Bt,
    unsigned short* __restrict__ oQ,
    unsigned short* __restrict__ oK,
    unsigned short* __restrict__ oV,   // MODE 0: Vt layout [bh][hd][s]
    float* __restrict__ outF,
    const float* __restrict__ bias,
    int M, int N, int K) {
  __shared__ __attribute__((aligned(16))) unsigned short smem[16384];
  const int tid = threadIdx.x;
  const int lane = tid & 63;
  const int w = tid >> 6;
  const int wm = w >> 1, wn = w & 1;
  const int quad = lane >> 4, l16 = lane & 15;

  // XCD-chunk swizzle (gridDim.x == 64): bijective bid -> (bx, by)
  const int bid = blockIdx.y * 64 + blockIdx.x;
  const int xcd = bid & 7;
  const int rr = bid >> 3;
  const int bx = xcd * 8 + (rr & 7);
  const int by = rr >> 3;
  const int m0 = bx * 128;
  const int n0 = by * 128;

  const int lr = lane >> 2;
  const int lc8 = (lane & 3) * 8;
  const unsigned short* gA0 = A + (size_t)(m0 + w * 32 + lr) * K + lc8;
  const unsigned short* gA1 = gA0 + (size_t)16 * K;
  const unsigned short* gB0 = Bt + (size_t)(n0 + w * 32 + lr) * K + lc8;
  const unsigned short* gB1 = gB0 + (size_t)16 * K;
  const int sA0o = (w * 2 + 0) * 512;          // within-buffer offsets (shorts)
  const int sA1o = (w * 2 + 1) * 512;
  const int sB0o = 4096 + (w * 2 + 0) * 512;
  const int sB1o = 4096 + (w * 2 + 1) * 512;

  f32x4 acc[4][4] = {};

  // prologue: stage k-tile 0 into buffer 0
  gl_lds16(gA0, smem + sA0o);
  gl_lds16(gA1, smem + sA1o);
  gl_lds16(gB0, smem + sB0o);
  gl_lds16(gB1, smem + sB1o);
  __syncthreads();

  for (int k0 = 0; k0 < K; k0 += 32) {
    const int cb = ((k0 >> 5) & 1) << 13;      // current buffer base (0 / 8192)
    const int nb = 8192 - cb;                  // next buffer base
    if (k0 + 32 < K) {                         // prefetch next k-tile (issue early)
      gl_lds16(gA0 + k0 + 32, smem + nb + sA0o);
      gl_lds16(gA1 + k0 + 32, smem + nb + sA1o);
      gl_lds16(gB0 + k0 + 32, smem + nb + sB0o);
      gl_lds16(gB1 + k0 + 32, smem + nb + sB1o);
    }
    short8 af[4], bfr[4];
#pragma unroll
    for (int mi = 0; mi < 4; mi++)
      af[mi] = *(const short8*)(smem + cb + (wm * 64 + mi * 16 + l16) * 32 + quad * 8);
#pragma unroll
    for (int ni = 0; ni < 4; ni++)
      bfr[ni] = *(const short8*)(smem + cb + 4096 + (wn * 64 + ni * 16 + l16) * 32 + quad * 8);
#pragma unroll
    for (int mi = 0; mi < 4; mi++)
#pragma unroll
      for (int ni = 0; ni < 4; ni++)
        acc[mi][ni] = __builtin_amdgcn_mfma_f32_16x16x32_bf16(af[mi], bfr[ni], acc[mi][ni], 0, 0, 0);
    __syncthreads();
  }

  if (MODE == 0) {
    const int which = n0 >> 10;                 // block-uniform: 0=Q,1=K,2=V
    if (which == 2) {
      // ---- V: stage C-tile in LDS (swizzled), write transposed to Vt ----
#pragma unroll
      for (int mi = 0; mi < 4; mi++)
#pragma unroll
        for (int ni = 0; ni < 4; ni++)
#pragma unroll
          for (int r = 0; r < 4; r++)
            smem[cswz(wm * 64 + mi * 16 + quad * 4 + r, wn * 64 + ni * 16 + l16)] =
                f32_bf16(acc[mi][ni][r]);
      __syncthreads();
      const int b = m0 >> 11, sb = m0 & 2047;
#pragma unroll
      for (int i = 0; i < 8; i++) {
        int c = tid + i * 256;                  // 0..2047
        int cl = c >> 4;                        // local col (feature) 0..127
        int sc = (c & 15) * 8;                  // local row (token) chunk
        int col = n0 + cl;
        int hh = (col >> 6) & 15, hd = col & 63;
        union { unsigned short u[8]; uint4 v; } t;
#pragma unroll
        for (int jx = 0; jx < 8; jx++) t.u[jx] = smem[cswz(sc + jx, cl)];
        *(uint4*)(oV + (((size_t)(b * NHD + hh)) * HD + hd) * S_ + sb + sc) = t.v;
      }
    } else {
      unsigned short* dst0 = which == 0 ? oQ : oK;
#pragma unroll
      for (int mi = 0; mi < 4; mi++)
#pragma unroll
        for (int ni = 0; ni < 4; ni++) {
          const int col = n0 + wn * 64 + ni * 16 + l16;
          const int hh = (col >> 6) & 15, hd = col & 63;
#pragma unroll
          for (int r = 0; r < 4; r++) {
            const int row = m0 + wm * 64 + mi * 16 + quad * 4 + r;
            int b = row >> 11, s = row & 2047;
            dst0[(((size_t)(b * NHD + hh)) * S_ + s) * HD + hd] = f32_bf16(acc[mi][ni][r]);
          }
        }
    }
  } else {
#pragma unroll
    for (int mi = 0; mi < 4; mi++)
#pragma unroll
      for (int ni = 0; ni < 4; ni++) {
        const int col = n0 + wn * 64 + ni * 16 + l16;
        float bv = bias[col];
#pragma unroll
        for (int r = 0; r < 4; r++) {
          const int row = m0 + wm * 64 + mi * 16 + quad * 4 + r;
          outF[(size_t)row * N + col] = acc[mi][ni][r] + bv;
        }
      }
  }
}

// ---------- flash attention, causal — balanced two-phase complement schedule ----
// Round-5 structure (proven): 512 blocks = 64 bh x 8 jj, 4 waves/block,
// 32 q-rows/wave. Phase 0: qc = 8jj+w; phase 1: qc = 63-8jj-w. Every qc once;
// per-block iters = 34 uniform; every wave computes 33 tiles.
// This round: LDS diet 50 KB -> 32 KB (epilogue staged in the K/V region,
// dead after the loop's final barrier) + __launch_bounds__(256,4):
// 4 blocks/CU = 16 waves/CU (was 2 blocks/8 waves) for the latency-bound loop.
// bh-grouped XCD mapping keeps 8 bh (4 MB K/V) per XCD L2 (FETCH 31->24.6 MB).
// Softmax: in-register P (cvt_pk+permlane32_swap), defer-max THR=8, max3.
__global__ __launch_bounds__(256, 4) void attn_kernel(
    const unsigned short* __restrict__ Q,
    const unsigned short* __restrict__ Kmat,
    const unsigned short* __restrict__ Vt,
    unsigned short* __restrict__ ctx) {
  // 32 KB total. Ks[b] = smem + b*4096, Vs[b] = smem + 8192 + b*4096.
  // Epilogue overlay (after final barrier): myP = smem + w*(32*72), 18 KB used.
  __shared__ __attribute__((aligned(16))) unsigned short smem[16384];

  const int tid = threadIdx.x;
  const int lane = tid & 63;
  const int w = tid >> 6;          // 0..3
  const int l32 = lane & 31;
  const int h = lane >> 5;

  const int bid = blockIdx.x;                        // 512 blocks
  const int bh = (bid & 7) * 8 + ((bid >> 3) & 7);   // 8 bh per XCD
  const int jj = bid >> 6;                           // 0..7

  const unsigned short* Qh = Q + (size_t)bh * S_ * HD;
  const unsigned short* Kh = Kmat + (size_t)bh * S_ * HD;
  const unsigned short* Vh = Vt + (size_t)bh * HD * S_;

  // staging map (256 threads): thread -> row sr, two 16B chunks jA/jB, XOR-swizzled
  const int sr = tid >> 2;                 // 0..63
  const int jA = tid & 3, jB = jA + 4;     // chunk ids
  const int sswA = sr * 64 + ((jA ^ (sr & 7)) << 3);
  const int sswB = sr * 64 + ((jB ^ (sr & 7)) << 3);
  const unsigned short* gKA = Kh + (size_t)sr * HD + jA * 8;   // + kt*64*HD
  const unsigned short* gKB = Kh + (size_t)sr * HD + jB * 8;
  const unsigned short* gVA = Vh + (size_t)sr * S_ + jA * 8;   // + kt*64
  const unsigned short* gVB = Vh + (size_t)sr * S_ + jB * 8;
  const int swz = (l32 & 7);               // fragment-read swizzle key

  unsigned short* myP = smem + (size_t)(w * 32) * 72;   // epilogue overlay
  const float scl = 0.18033688f;   // (1/sqrt(64)) * log2(e)
  const int b = bh >> 4, head = bh & 15;

  for (int ph = 0; ph < 2; ph++) {
    const int qc = (ph == 0) ? (jj * 8 + w) : (63 - jj * 8 - w);
    const int nt = (qc >> 1) + 1;                         // this wave's tiles
    const int ntmax = (ph == 0) ? (jj * 4 + 2) : (32 - jj * 4);  // block iters
    const int qrow = qc * 32 + l32;

    short8 qf[4];
#pragma unroll
    for (int ks = 0; ks < 4; ks++)
      qf[ks] = *(const short8*)(Qh + (size_t)qrow * HD + ks * 16 + h * 8);

    // stage tile 0 (each thread writes only its own LDS chunks -> race-free)
    uint4 kregA = *(const uint4*)gKA, kregB = *(const uint4*)gKB;
    uint4 vregA = *(const uint4*)gVA, vregB = *(const uint4*)gVB;
    *(uint4*)(smem + sswA) = kregA;
    *(uint4*)(smem + sswB) = kregB;
    *(uint4*)(smem + 8192 + sswA) = vregA;
    *(uint4*)(smem + 8192 + sswB) = vregB;
    __syncthreads();

    f32x16 oacc[2] = {};
    float m_run = -__builtin_inff();
    float l_run = 0.f;

    for (int kt = 0; kt < ntmax; kt++) {
      // prefetch next tile into regs (lands during compute)
      if (kt + 1 < ntmax) {
        kregA = *(const uint4*)(gKA + (size_t)(kt + 1) * 64 * HD);
        kregB = *(const uint4*)(gKB + (size_t)(kt + 1) * 64 * HD);
        vregA = *(const uint4*)(gVA + (size_t)(kt + 1) * 64);
        vregB = *(const uint4*)(gVB + (size_t)(kt + 1) * 64);
      }
      const unsigned short* Kb_ = smem + ((kt & 1) << 12);
      const unsigned short* Vb_ = smem + 8192 + ((kt & 1) << 12);

      if (kt < nt) {
        const int k0 = kt * 64;
        // ---- S^T = K * Q^T (fragments from swizzled LDS) ----
        f32x16 sacc[2] = {};
#pragma unroll
        for (int ks = 0; ks < 4; ks++)
#pragma unroll
          for (int mi = 0; mi < 2; mi++) {
            short8 kf = *(const short8*)(Kb_ + (mi * 32 + l32) * 64 + (((ks * 2 + h) ^ swz) << 3));
            sacc[mi] = __builtin_amdgcn_mfma_f32_32x32x16_bf16(kf, qf[ks], sacc[mi], 0, 0, 0);
          }

        // ---- online softmax (defer-max, max3 reduce) ----
        if (kt == nt - 1) {
#pragma unroll
          for (int mi = 0; mi < 2; mi++)
#pragma unroll
            for (int e = 0; e < 16; e++) {
              int key = k0 + mi * 32 + (e & 3) + 8 * (e >> 2) + 4 * h;
              if (key > qrow) sacc[mi][e] = -__builtin_inff();
            }
        }
        float vmax = fmaxf(sacc[0][0], sacc[0][1]);
#pragma unroll
        for (int e = 2; e < 16; e += 2) vmax = max3f(vmax, sacc[0][e], sacc[0][e + 1]);
#pragma unroll
        for (int e = 0; e < 16; e += 2) vmax = max3f(vmax, sacc[1][e], sacc[1][e + 1]);
        vmax = fmaxf(vmax, __shfl_xor(vmax, 32));
        const float pm = vmax * scl;
        if (!__all(pm <= m_run + 8.f)) {
          const float mnew = fmaxf(m_run, pm);
          const float alpha = EXP2(m_run - mnew);
          m_run = mnew;
          l_run *= alpha;
#pragma unroll
          for (int mi = 0; mi < 2; mi++) oacc[mi] *= alpha;
        }

        float rs = 0.f;
#pragma unroll
        for (int mi = 0; mi < 2; mi++)
#pragma unroll
          for (int e = 0; e < 16; e++) {
            float p = EXP2(fmaf(sacc[mi][e], scl, -m_run));
            sacc[mi][e] = p;
            rs += p;
          }
        rs += __shfl_xor(rs, 32);
        l_run += rs;

        // ---- P -> bf16 PV B-fragments, fully in-register ----
        short8 pfr[4];
#pragma unroll
        for (int mi = 0; mi < 2; mi++) {
          unsigned w0 = cvt_pk_bf16(sacc[mi][0], sacc[mi][1]);
          unsigned w1 = cvt_pk_bf16(sacc[mi][2], sacc[mi][3]);
          unsigned w2 = cvt_pk_bf16(sacc[mi][4], sacc[mi][5]);
          unsigned w3 = cvt_pk_bf16(sacc[mi][6], sacc[mi][7]);
          pl32swap(w0, w2);
          pl32swap(w1, w3);
          union { unsigned u[4]; short8 s; } lo;
          lo.u[0] = w0; lo.u[1] = w1; lo.u[2] = w2; lo.u[3] = w3;
          pfr[2 * mi + 0] = lo.s;
          unsigned x0 = cvt_pk_bf16(sacc[mi][8], sacc[mi][9]);
          unsigned x1 = cvt_pk_bf16(sacc[mi][10], sacc[mi][11]);
          unsigned x2 = cvt_pk_bf16(sacc[mi][12], sacc[mi][13]);
          unsigned x3 = cvt_pk_bf16(sacc[mi][14], sacc[mi][15]);
          pl32swap(x0, x2);
          pl32swap(x1, x3);
          union { unsigned u[4]; short8 s; } hi;
          hi.u[0] = x0; hi.u[1] = x1; hi.u[2] = x2; hi.u[3] = x3;
          pfr[2 * mi + 1] = hi.s;
        }

        // ---- O^T += V^T * P^T (V fragments from swizzled LDS) ----
#pragma unroll
        for (int ks2 = 0; ks2 < 4; ks2++) {
#pragma unroll
          for (int mi2 = 0; mi2 < 2; mi2++) {
            short8 vf = *(const short8*)(Vb_ + (mi2 * 32 + l32) * 64 + (((ks2 * 2 + h) ^ swz) << 3));
            oacc[mi2] = __builtin_amdgcn_mfma_f32_32x32x16_bf16(vf, pfr[ks2], oacc[mi2], 0, 0, 0);
          }
        }
      }

      // write next tile into the other buffer (its readers passed the previous
      // barrier), then one barrier makes it visible for iter kt+1
      if (kt + 1 < ntmax) {
        *(uint4*)(smem + ((~kt & 1) << 12) + sswA) = kregA;
        *(uint4*)(smem + ((~kt & 1) << 12) + sswB) = kregB;
        *(uint4*)(smem + 8192 + ((~kt & 1) << 12) + sswA) = vregA;
        *(uint4*)(smem + 8192 + ((~kt & 1) << 12) + sswB) = vregB;
      }
      __syncthreads();
    }

    // ---- epilogue: O^T / l -> LDS overlay (K/V dead) -> coalesced stores ----
    const float inv = 1.f / l_run;
#pragma unroll
    for (int mi2 = 0; mi2 < 2; mi2++)
#pragma unroll
      for (int g = 0; g < 4; g++) {
        uint2 pk;
        pk.x = cvt_pk_bf16(oacc[mi2][4 * g + 0] * inv, oacc[mi2][4 * g + 1] * inv);
        pk.y = cvt_pk_bf16(oacc[mi2][4 * g + 2] * inv, oacc[mi2][4 * g + 3] * inv);
        *(uint2*)(myP + l32 * 72 + mi2 * 32 + g * 8 + h * 4) = pk;
      }
#pragma unroll
    for (int p = 0; p < 4; p++) {
      int r = p * 8 + (lane >> 3);
      int c = (lane & 7) * 8;
      uint4 vv = *(const uint4*)(myP + r * 72 + c);
      *(uint4*)(ctx + ((size_t)(b * S_ + qc * 32 + r)) * DOUT + head * 64 + c) = vv;
    }
    // all waves must finish reading the overlay before phase 1 re-stages K/V
    __syncthreads();
  }
}

extern "C" void kernel_launch(void* const* d_in, const int* in_sizes, int n_in,
                              void* d_out, int out_size, void* d_ws, size_t ws_size,
                              hipStream_t stream) {
  const float* x  = (const float*)d_in[0];
  const float* Wq = (const float*)d_in[1];
  const float* Wk = (const float*)d_in[2];
  const float* Wv = (const float*)d_in[3];
  const float* Wo = (const float*)d_in[4];
  const float* bo = (const float*)d_in[5];
  float* out = (float*)d_out;
  char* ws = (char*)d_ws;

  const size_t MB = 1024 * 1024;
  unsigned short* Wqt = (unsigned short*)(ws + 0 * MB);
  unsigned short* Wkt = (unsigned short*)(ws + 2 * MB);
  unsigned short* Wvt = (unsigned short*)(ws + 4 * MB);
  unsigned short* Wot = (unsigned short*)(ws + 6 * MB);
  unsigned short* xb  = (unsigned short*)(ws + 8 * MB);
  unsigned short* Qb  = (unsigned short*)(ws + 24 * MB);
  unsigned short* Kb  = (unsigned short*)(ws + 40 * MB);
  unsigned short* Vtb = (unsigned short*)(ws + 72 * MB);  // Vt [bh][hd][s], written by GEMM
  unsigned short* ctxb = xb;   // xb dead after QKV GEMM

  cvt_kernel<<<8192, 256, 0, stream>>>(x, xb, 2097152);
  wtrans4_kernel<<<dim3(16, 16, 4), 256, 0, stream>>>(Wq, Wk, Wv, Wo, Wqt, Wkt, Wvt, Wot);
  gemm_kernel<0><<<dim3(64, 24), 256, 0, stream>>>(xb, Wqt, Qb, Kb, Vtb, nullptr, nullptr,
                                                   8192, 3072, 1024);
  attn_kernel<<<512, 256, 0, stream>>>(Qb, Kb, Vtb, ctxb);
  gemm_kernel<1><<<dim3(64, 8), 256, 0, stream>>>(ctxb, Wot, nullptr, nullptr, nullptr, out, bo,
                                                  8192, 1024, 1024);
}

// Round 10
// 236.090 us; speedup vs baseline: 1.1018x; 1.1018x over previous
//
#include <hip/hip_runtime.h>
#include <stdint.h>

#define B_   4
#define S_   2048
#define DI   1024
#define DOUT 1024
#define NHD  16
#define HD   64

typedef __attribute__((ext_vector_type(8))) short short8;
typedef __attribute__((ext_vector_type(4))) float f32x4;
typedef __attribute__((ext_vector_type(16))) float f32x16;

__device__ __forceinline__ unsigned short f32_bf16(float f) {
  union { float f; unsigned u; } v; v.f = f;
  unsigned r = v.u + 0x7FFFu + ((v.u >> 16) & 1u);   // RNE
  return (unsigned short)(r >> 16);
}

// packed f32x2 -> bf16x2 (dst.lo = bf16(a), dst.hi = bf16(b))
__device__ __forceinline__ unsigned cvt_pk_bf16(float a, float b) {
  unsigned r;
  asm("v_cvt_pk_bf16_f32 %0, %1, %2" : "=v"(r) : "v"(a), "v"(b));
  return r;
}

// v_permlane32_swap_b32 a, b:  a.row1 <-> b.row0  (rows = 32-lane halves)
__device__ __forceinline__ void pl32swap(unsigned &dst, unsigned &src) {
  asm("v_permlane32_swap_b32 %0, %1" : "+v"(dst), "+v"(src));
}

__device__ __forceinline__ float max3f(float a, float b, float c) {
  float d;
  asm("v_max3_f32 %0, %1, %2, %3" : "=v"(d) : "v"(a), "v"(b), "v"(c));
  return d;
}

// async 16B global->LDS (dst wave-uniform; HW adds lane*16)
__device__ __forceinline__ void gl_lds16(const void* g, void* s) {
  __builtin_amdgcn_global_load_lds(
      (const __attribute__((address_space(1))) unsigned int*)g,
      (__attribute__((address_space(3))) unsigned int*)s, 16, 0, 0);
}

#define EXP2(x) __builtin_amdgcn_exp2f(x)

// ---------- elementwise fp32 -> bf16 ----------
__global__ __launch_bounds__(256) void cvt_kernel(const float* __restrict__ src,
                                                  unsigned short* __restrict__ dst, int n4) {
  int i = blockIdx.x * blockDim.x + threadIdx.x;
  if (i < n4) {
    float4 v = ((const float4*)src)[i];
    ushort4 o;
    o.x = f32_bf16(v.x); o.y = f32_bf16(v.y); o.z = f32_bf16(v.z); o.w = f32_bf16(v.w);
    ((ushort4*)dst)[i] = o;
  }
}

// ---------- weight transpose+convert x4: W[k][n] f32 -> Wt[n][k] bf16 ----------
__global__ __launch_bounds__(256) void wtrans4_kernel(
    const float* __restrict__ W0, const float* __restrict__ W1,
    const float* __restrict__ W2, const float* __restrict__ W3,
    unsigned short* __restrict__ T0, unsigned short* __restrict__ T1,
    unsigned short* __restrict__ T2, unsigned short* __restrict__ T3) {
  __shared__ __attribute__((aligned(16))) float tile[64][65];
  const int z = blockIdx.z;
  const float* W = z == 0 ? W0 : z == 1 ? W1 : z == 2 ? W2 : W3;
  unsigned short* Wt = z == 0 ? T0 : z == 1 ? T1 : z == 2 ? T2 : T3;
  const int k0 = blockIdx.y * 64;
  const int n0 = blockIdx.x * 64;
  const int tid = threadIdx.x;
#pragma unroll
  for (int i = 0; i < 4; i++) {
    int c = tid + i * 256;
    int r = c >> 4;
    int cc = (c & 15) * 4;
    float4 v = *(const float4*)(W + (size_t)(k0 + r) * DOUT + n0 + cc);
    tile[r][cc] = v.x; tile[r][cc + 1] = v.y; tile[r][cc + 2] = v.z; tile[r][cc + 3] = v.w;
  }
  __syncthreads();
#pragma unroll
  for (int i = 0; i < 4; i++) {
    int c = tid + i * 256;
    int r = c >> 4;
    int cc = (c & 15) * 4;
    ushort4 o;
    o.x = f32_bf16(tile[cc + 0][r]);
    o.y = f32_bf16(tile[cc + 1][r]);
    o.z = f32_bf16(tile[cc + 2][r]);
    o.w = f32_bf16(tile[cc + 3][r]);
    *(ushort4*)(Wt + (size_t)(n0 + r) * DI + k0 + cc) = o;
  }
}

// swizzled index into the 128x128 bf16 C-stage tile (16B-chunk XOR swizzle).
__device__ __forceinline__ int cswz(int r, int c) {
  return r * 128 + ((((c >> 3) ^ ((r >> 3) & 15)) << 3) | (c & 7));
}

// ---------- GEMM (round-5 proven: m97 recipe + stage-early double-buffer) ----
// + bijective XCD-chunk swizzle. MODE 0: fused QKV (N=3072); Q/K scatter
// head-major, V written transposed to Vt[bh][hd][s]. MODE 1: fp32 + bias.
template <int MODE>
__global__ __launch_bounds__(256) void gemm_kernel(
    const unsigned short* __restrict__ A,
    const unsigned short* __restrict__ Bt,
    unsigned short* __restrict__ oQ,
    unsigned short* __restrict__ oK,
    unsigned short* __restrict__ oV,   // MODE 0: Vt layout [bh][hd][s]
    float* __restrict__ outF,
    const float* __restrict__ bias,
    int M, int N, int K) {
  __shared__ __attribute__((aligned(16))) unsigned short smem[16384];
  const int tid = threadIdx.x;
  const int lane = tid & 63;
  const int w = tid >> 6;
  const int wm = w >> 1, wn = w & 1;
  const int quad = lane >> 4, l16 = lane & 15;

  // XCD-chunk swizzle (gridDim.x == 64): bijective bid -> (bx, by)
  const int bid = blockIdx.y * 64 + blockIdx.x;
  const int xcd = bid & 7;
  const int rr = bid >> 3;
  const int bx = xcd * 8 + (rr & 7);
  const int by = rr >> 3;
  const int m0 = bx * 128;
  const int n0 = by * 128;

  const int lr = lane >> 2;
  const int lc8 = (lane & 3) * 8;
  const unsigned short* gA0 = A + (size_t)(m0 + w * 32 + lr) * K + lc8;
  const unsigned short* gA1 = gA0 + (size_t)16 * K;
  const unsigned short* gB0 = Bt + (size_t)(n0 + w * 32 + lr) * K + lc8;
  const unsigned short* gB1 = gB0 + (size_t)16 * K;
  const int sA0o = (w * 2 + 0) * 512;          // within-buffer offsets (shorts)
  const int sA1o = (w * 2 + 1) * 512;
  const int sB0o = 4096 + (w * 2 + 0) * 512;
  const int sB1o = 4096 + (w * 2 + 1) * 512;

  f32x4 acc[4][4] = {};

  // prologue: stage k-tile 0 into buffer 0
  gl_lds16(gA0, smem + sA0o);
  gl_lds16(gA1, smem + sA1o);
  gl_lds16(gB0, smem + sB0o);
  gl_lds16(gB1, smem + sB1o);
  __syncthreads();

  for (int k0 = 0; k0 < K; k0 += 32) {
    const int cb = ((k0 >> 5) & 1) << 13;      // current buffer base (0 / 8192)
    const int nb = 8192 - cb;                  // next buffer base
    if (k0 + 32 < K) {                         // prefetch next k-tile (issue early)
      gl_lds16(gA0 + k0 + 32, smem + nb + sA0o);
      gl_lds16(gA1 + k0 + 32, smem + nb + sA1o);
      gl_lds16(gB0 + k0 + 32, smem + nb + sB0o);
      gl_lds16(gB1 + k0 + 32, smem + nb + sB1o);
    }
    short8 af[4], bfr[4];
#pragma unroll
    for (int mi = 0; mi < 4; mi++)
      af[mi] = *(const short8*)(smem + cb + (wm * 64 + mi * 16 + l16) * 32 + quad * 8);
#pragma unroll
    for (int ni = 0; ni < 4; ni++)
      bfr[ni] = *(const short8*)(smem + cb + 4096 + (wn * 64 + ni * 16 + l16) * 32 + quad * 8);
#pragma unroll
    for (int mi = 0; mi < 4; mi++)
#pragma unroll
      for (int ni = 0; ni < 4; ni++)
        acc[mi][ni] = __builtin_amdgcn_mfma_f32_16x16x32_bf16(af[mi], bfr[ni], acc[mi][ni], 0, 0, 0);
    __syncthreads();
  }

  if (MODE == 0) {
    const int which = n0 >> 10;                 // block-uniform: 0=Q,1=K,2=V
    if (which == 2) {
      // ---- V: stage C-tile in LDS (swizzled), write transposed to Vt ----
#pragma unroll
      for (int mi = 0; mi < 4; mi++)
#pragma unroll
        for (int ni = 0; ni < 4; ni++)
#pragma unroll
          for (int r = 0; r < 4; r++)
            smem[cswz(wm * 64 + mi * 16 + quad * 4 + r, wn * 64 + ni * 16 + l16)] =
                f32_bf16(acc[mi][ni][r]);
      __syncthreads();
      const int b = m0 >> 11, sb = m0 & 2047;
#pragma unroll
      for (int i = 0; i < 8; i++) {
        int c = tid + i * 256;                  // 0..2047
        int cl = c >> 4;                        // local col (feature) 0..127
        int sc = (c & 15) * 8;                  // local row (token) chunk
        int col = n0 + cl;
        int hh = (col >> 6) & 15, hd = col & 63;
        union { unsigned short u[8]; uint4 v; } t;
#pragma unroll
        for (int jx = 0; jx < 8; jx++) t.u[jx] = smem[cswz(sc + jx, cl)];
        *(uint4*)(oV + (((size_t)(b * NHD + hh)) * HD + hd) * S_ + sb + sc) = t.v;
      }
    } else {
      unsigned short* dst0 = which == 0 ? oQ : oK;
#pragma unroll
      for (int mi = 0; mi < 4; mi++)
#pragma unroll
        for (int ni = 0; ni < 4; ni++) {
          const int col = n0 + wn * 64 + ni * 16 + l16;
          const int hh = (col >> 6) & 15, hd = col & 63;
#pragma unroll
          for (int r = 0; r < 4; r++) {
            const int row = m0 + wm * 64 + mi * 16 + quad * 4 + r;
            int b = row >> 11, s = row & 2047;
            dst0[(((size_t)(b * NHD + hh)) * S_ + s) * HD + hd] = f32_bf16(acc[mi][ni][r]);
          }
        }
    }
  } else {
#pragma unroll
    for (int mi = 0; mi < 4; mi++)
#pragma unroll
      for (int ni = 0; ni < 4; ni++) {
        const int col = n0 + wn * 64 + ni * 16 + l16;
        float bv = bias[col];
#pragma unroll
        for (int r = 0; r < 4; r++) {
          const int row = m0 + wm * 64 + mi * 16 + quad * 4 + r;
          outF[(size_t)row * N + col] = acc[mi][ni][r] + bv;
        }
      }
  }
}

// ---------- flash attention, causal — balanced two-phase complement schedule ----
// 512 blocks = 64 bh x 8 jj, 4 waves, 32 q-rows/wave; per-block iters uniform.
// This round: K/V staging via global_load_lds with PRE-SWIZZLED per-lane
// SOURCE (LDS dest linear; data for row r, chunk j lands at chunk r*8+(j^(r&7)),
// matching the existing swizzled fragment reads) — removes the 16-VGPR reg
// prefetch + 8 ds_writes/iter so VGPR fits <=128 naturally (no forced cap;
// round-9 lesson: launch_bounds(256,4) caused spills, FETCH/WRITE blowup).
// LDS 32 KB (epilogue overlaid on dead K/V region) -> up to 4-5 blocks/CU.
// Softmax: in-register P (cvt_pk+permlane32_swap), defer-max THR=8, max3.
__global__ __launch_bounds__(256, 2) void attn_kernel(
    const unsigned short* __restrict__ Q,
    const unsigned short* __restrict__ Kmat,
    const unsigned short* __restrict__ Vt,
    unsigned short* __restrict__ ctx) {
  // 32 KB. K buffers at shorts 0 / 4096; V buffers at 8192 / 12288.
  // Epilogue overlay (after final barrier): myP = smem + w*32*72 (18 KB used).
  __shared__ __attribute__((aligned(16))) unsigned short smem[16384];

  const int tid = threadIdx.x;
  const int lane = tid & 63;
  const int w = tid >> 6;          // 0..3
  const int l32 = lane & 31;
  const int h = lane >> 5;

  const int bid = blockIdx.x;                        // 512 blocks
  const int bh = (bid & 7) * 8 + ((bid >> 3) & 7);   // 8 bh per XCD
  const int jj = bid >> 6;                           // 0..7

  const unsigned short* Qh = Q + (size_t)bh * S_ * HD;
  const unsigned short* Kh = Kmat + (size_t)bh * S_ * HD;
  const unsigned short* Vh = Vt + (size_t)bh * HD * S_;

  // async staging map: thread tid owns LDS chunks tid and tid+256 (linear).
  // chunk q -> row r=q>>3, slot c=q&7; source chunk j = c ^ (r&7).
  const int r1 = tid >> 3, c1 = tid & 7;
  const int sj1 = c1 ^ (r1 & 7);
  const unsigned short* gK1 = Kh + (size_t)r1 * HD + sj1 * 8;   // + kt*64*HD
  const unsigned short* gV1 = Vh + (size_t)r1 * S_ + sj1 * 8;   // + kt*64
  const int swz = (l32 & 7);               // fragment-read swizzle key

  unsigned short* myP = smem + (size_t)(w * 32) * 72;   // epilogue overlay
  const float scl = 0.18033688f;   // (1/sqrt(64)) * log2(e)
  const int b = bh >> 4, head = bh & 15;

  // stage tile t into buffer bf (LDS dest wave-uniform base + lane*16)
#define ASTAGE(t, bf)                                                       \
  do {                                                                      \
    const unsigned short* k_ = gK1 + (size_t)(t) * 64 * HD;                 \
    const unsigned short* v_ = gV1 + (size_t)(t) * 64;                      \
    gl_lds16(k_, smem + (bf) * 4096 + w * 512);                             \
    gl_lds16(k_ + 32 * HD, smem + (bf) * 4096 + 2048 + w * 512);            \
    gl_lds16(v_, smem + 8192 + (bf) * 4096 + w * 512);                      \
    gl_lds16(v_ + (size_t)32 * S_, smem + 8192 + (bf) * 4096 + 2048 + w * 512); \
  } while (0)

  for (int ph = 0; ph < 2; ph++) {
    const int qc = (ph == 0) ? (jj * 8 + w) : (63 - jj * 8 - w);
    const int nt = (qc >> 1) + 1;                         // this wave's tiles
    const int ntmax = (ph == 0) ? (jj * 4 + 2) : (32 - jj * 4);  // block iters
    const int qrow = qc * 32 + l32;

    short8 qf[4];
#pragma unroll
    for (int ks = 0; ks < 4; ks++)
      qf[ks] = *(const short8*)(Qh + (size_t)qrow * HD + ks * 16 + h * 8);

    ASTAGE(0, 0);
    __syncthreads();

    f32x16 oacc[2] = {};
    float m_run = -__builtin_inff();
    float l_run = 0.f;

    for (int kt = 0; kt < ntmax; kt++) {
      // issue next tile's async staging early (other buffer; its readers
      // passed the barrier at end of iter kt-1)
      if (kt + 1 < ntmax) ASTAGE(kt + 1, (kt + 1) & 1);

      const unsigned short* Kb_ = smem + ((kt & 1) << 12);
      const unsigned short* Vb_ = smem + 8192 + ((kt & 1) << 12);

      if (kt < nt) {
        const int k0 = kt * 64;
        // ---- S^T = K * Q^T (fragments from swizzled LDS) ----
        f32x16 sacc[2] = {};
#pragma unroll
        for (int ks = 0; ks < 4; ks++)
#pragma unroll
          for (int mi = 0; mi < 2; mi++) {
            short8 kf = *(const short8*)(Kb_ + (mi * 32 + l32) * 64 + (((ks * 2 + h) ^ swz) << 3));
            sacc[mi] = __builtin_amdgcn_mfma_f32_32x32x16_bf16(kf, qf[ks], sacc[mi], 0, 0, 0);
          }

        // ---- online softmax (defer-max, max3 reduce) ----
        if (kt == nt - 1) {
#pragma unroll
          for (int mi = 0; mi < 2; mi++)
#pragma unroll
            for (int e = 0; e < 16; e++) {
              int key = k0 + mi * 32 + (e & 3) + 8 * (e >> 2) + 4 * h;
              if (key > qrow) sacc[mi][e] = -__builtin_inff();
            }
        }
        float vmax = fmaxf(sacc[0][0], sacc[0][1]);
#pragma unroll
        for (int e = 2; e < 16; e += 2) vmax = max3f(vmax, sacc[0][e], sacc[0][e + 1]);
#pragma unroll
        for (int e = 0; e < 16; e += 2) vmax = max3f(vmax, sacc[1][e], sacc[1][e + 1]);
        vmax = fmaxf(vmax, __shfl_xor(vmax, 32));
        const float pm = vmax * scl;
        if (!__all(pm <= m_run + 8.f)) {
          const float mnew = fmaxf(m_run, pm);
          const float alpha = EXP2(m_run - mnew);
          m_run = mnew;
          l_run *= alpha;
#pragma unroll
          for (int mi = 0; mi < 2; mi++) oacc[mi] *= alpha;
        }

        float rs = 0.f;
#pragma unroll
        for (int mi = 0; mi < 2; mi++)
#pragma unroll
          for (int e = 0; e < 16; e++) {
            float p = EXP2(fmaf(sacc[mi][e], scl, -m_run));
            sacc[mi][e] = p;
            rs += p;
          }
        rs += __shfl_xor(rs, 32);
        l_run += rs;

        // ---- P -> bf16 PV B-fragments, fully in-register ----
        short8 pfr[4];
#pragma unroll
        for (int mi = 0; mi < 2; mi++) {
          unsigned w0 = cvt_pk_bf16(sacc[mi][0], sacc[mi][1]);
          unsigned w1 = cvt_pk_bf16(sacc[mi][2], sacc[mi][3]);
          unsigned w2 = cvt_pk_bf16(sacc[mi][4], sacc[mi][5]);
          unsigned w3 = cvt_pk_bf16(sacc[mi][6], sacc[mi][7]);
          pl32swap(w0, w2);
          pl32swap(w1, w3);
          union { unsigned u[4]; short8 s; } lo;
          lo.u[0] = w0; lo.u[1] = w1; lo.u[2] = w2; lo.u[3] = w3;
          pfr[2 * mi + 0] = lo.s;
          unsigned x0 = cvt_pk_bf16(sacc[mi][8], sacc[mi][9]);
          unsigned x1 = cvt_pk_bf16(sacc[mi][10], sacc[mi][11]);
          unsigned x2 = cvt_pk_bf16(sacc[mi][12], sacc[mi][13]);
          unsigned x3 = cvt_pk_bf16(sacc[mi][14], sacc[mi][15]);
          pl32swap(x0, x2);
          pl32swap(x1, x3);
          union { unsigned u[4]; short8 s; } hi;
          hi.u[0] = x0; hi.u[1] = x1; hi.u[2] = x2; hi.u[3] = x3;
          pfr[2 * mi + 1] = hi.s;
        }

        // ---- O^T += V^T * P^T (V fragments from swizzled LDS) ----
#pragma unroll
        for (int ks2 = 0; ks2 < 4; ks2++) {
#pragma unroll
          for (int mi2 = 0; mi2 < 2; mi2++) {
            short8 vf = *(const short8*)(Vb_ + (mi2 * 32 + l32) * 64 + (((ks2 * 2 + h) ^ swz) << 3));
            oacc[mi2] = __builtin_amdgcn_mfma_f32_32x32x16_bf16(vf, pfr[ks2], oacc[mi2], 0, 0, 0);
          }
        }
      }

      // one barrier/iter: drains this iter's async staging (vmcnt) and
      // everyone's reads of the buffer being re-staged next iter
      __syncthreads();
    }

    // ---- epilogue: O^T / l -> LDS overlay (K/V dead) -> coalesced stores ----
    const float inv = 1.f / l_run;
#pragma unroll
    for (int mi2 = 0; mi2 < 2; mi2++)
#pragma unroll
      for (int g = 0; g < 4; g++) {
        uint2 pk;
        pk.x = cvt_pk_bf16(oacc[mi2][4 * g + 0] * inv, oacc[mi2][4 * g + 1] * inv);
        pk.y = cvt_pk_bf16(oacc[mi2][4 * g + 2] * inv, oacc[mi2][4 * g + 3] * inv);
        *(uint2*)(myP + l32 * 72 + mi2 * 32 + g * 8 + h * 4) = pk;
      }
#pragma unroll
    for (int p = 0; p < 4; p++) {
      int r = p * 8 + (lane >> 3);
      int c = (lane & 7) * 8;
      uint4 vv = *(const uint4*)(myP + r * 72 + c);
      *(uint4*)(ctx + ((size_t)(b * S_ + qc * 32 + r)) * DOUT + head * 64 + c) = vv;
    }
    // all waves must finish reading the overlay before phase 1 re-stages K/V
    __syncthreads();
  }
#undef ASTAGE
}

extern "C" void kernel_launch(void* const* d_in, const int* in_sizes, int n_in,
                              void* d_out, int out_size, void* d_ws, size_t ws_size,
                              hipStream_t stream) {
  const float* x  = (const float*)d_in[0];
  const float* Wq = (const float*)d_in[1];
  const float* Wk = (const float*)d_in[2];
  const float* Wv = (const float*)d_in[3];
  const float* Wo = (const float*)d_in[4];
  const float* bo = (const float*)d_in[5];
  float* out = (float*)d_out;
  char* ws = (char*)d_ws;

  const size_t MB = 1024 * 1024;
  unsigned short* Wqt = (unsigned short*)(ws + 0 * MB);
  unsigned short* Wkt = (unsigned short*)(ws + 2 * MB);
  unsigned short* Wvt = (unsigned short*)(ws + 4 * MB);
  unsigned short* Wot = (unsigned short*)(ws + 6 * MB);
  unsigned short* xb  = (unsigned short*)(ws + 8 * MB);
  unsigned short* Qb  = (unsigned short*)(ws + 24 * MB);
  unsigned short* Kb  = (unsigned short*)(ws + 40 * MB);
  unsigned short* Vtb = (unsigned short*)(ws + 72 * MB);  // Vt [bh][hd][s], written by GEMM
  unsigned short* ctxb = xb;   // xb dead after QKV GEMM

  cvt_kernel<<<8192, 256, 0, stream>>>(x, xb, 2097152);
  wtrans4_kernel<<<dim3(16, 16, 4), 256, 0, stream>>>(Wq, Wk, Wv, Wo, Wqt, Wkt, Wvt, Wot);
  gemm_kernel<0><<<dim3(64, 24), 256, 0, stream>>>(xb, Wqt, Qb, Kb, Vtb, nullptr, nullptr,
                                                   8192, 3072, 1024);
  attn_kernel<<<512, 256, 0, stream>>>(Qb, Kb, Vtb, ctxb);
  gemm_kernel<1><<<dim3(64, 8), 256, 0, stream>>>(ctxb, Wot, nullptr, nullptr, nullptr, out, bo,
                                                  8192, 1024, 1024);
}